// Round 12
// baseline (2696.916 us; speedup 1.0000x reference)
//
#include <hip/hip_runtime.h>
#include <math.h>

#define BATCH 512
#define NG 16
#define GSZ 32
#define H 128
#define E 64
#define PRE 512
#define BOT 1024
#define MLPD 1024
#define SEQ 12
#define AK 1152   // Abf row length = H + BOT

typedef __attribute__((ext_vector_type(8))) short bf16x8;
typedef __attribute__((ext_vector_type(4))) float f32x4;

__device__ __forceinline__ unsigned short f2bf(float f) {
    unsigned u = __float_as_uint(f);
    u += 0x7FFF + ((u >> 16) & 1);   // round-to-nearest-even
    return (unsigned short)(u >> 16);
}
__device__ __forceinline__ float bf2f(unsigned short s) {
    return __uint_as_float(((unsigned)s) << 16);
}

#define GLB(p) ((const __attribute__((address_space(1))) unsigned int*)(p))
#define LDS(p) ((__attribute__((address_space(3))) unsigned int*)(p))

// ---------------------------------------------------------------- one-shot prep
#define N0 (BOT * PRE)        /* W2b   */
#define N1 (MLPD * AK)        /* Wm1b  */
#define N2 (H * MLPD)         /* Wm2b  */
#define N3 (PRE * H)          /* W1hb  */
#define N4 (PRE)              /* wc    */
#define N5 (BATCH * H)        /* c     */
#define N6 (BATCH * 2)        /* pos   */
#define N7 (512 * 192)        /* Wgb = [Wih|Whh] bf16 */
#define N8 (512)              /* bg = bih+bhh */
#define PREP_TOT (N0 + N1 + N2 + N3 + N4 + N5 + N6 + N7 + N8 + 1)

__global__ void prep_kernel(
    const float* __restrict__ W2, const float* __restrict__ Wm1,
    const float* __restrict__ Wm2, const float* __restrict__ W1,
    const float* __restrict__ Wp, const float* __restrict__ bp, const float* __restrict__ b1,
    const float* __restrict__ ch, const float* __restrict__ last_pos,
    const float* __restrict__ Wih, const float* __restrict__ Whh,
    const float* __restrict__ bih, const float* __restrict__ bhh,
    unsigned short* __restrict__ W2b, unsigned short* __restrict__ Wm1b,
    unsigned short* __restrict__ Wm2b, unsigned short* __restrict__ W1hb,
    float* __restrict__ Wcx, float* __restrict__ Wcy, float* __restrict__ biash,
    float* __restrict__ cbuf, float* __restrict__ pos,
    unsigned short* __restrict__ Wgb, float* __restrict__ bg,
    float* __restrict__ loss)
{
    long idx = (long)blockIdx.x * 256 + threadIdx.x;
    if (idx < N0) { W2b[idx] = f2bf(W2[idx]); return; }
    idx -= N0;
    if (idx < N1) { Wm1b[idx] = f2bf(Wm1[idx]); return; }
    idx -= N1;
    if (idx < N2) { Wm2b[idx] = f2bf(Wm2[idx]); return; }
    idx -= N2;
    if (idx < N3) { int r = (int)(idx >> 7), c = (int)(idx & 127);
                    W1hb[idx] = f2bf(W1[r * 192 + E + c]); return; }
    idx -= N3;
    if (idx < N4) {
        int p = (int)idx;
        float sx = 0.f, sy = 0.f, sb = 0.f;
#pragma unroll 8
        for (int e = 0; e < E; ++e) {
            float w = W1[p * 192 + e];
            sx += w * Wp[e * 2 + 0];
            sy += w * Wp[e * 2 + 1];
            sb += w * bp[e];
        }
        Wcx[p] = sx; Wcy[p] = sy; biash[p] = b1[p] + sb;
        return;
    }
    idx -= N4;
    if (idx < N5) { cbuf[idx] = ch[idx]; return; }
    idx -= N5;
    if (idx < N6) { pos[idx] = last_pos[idx]; return; }
    idx -= N6;
    if (idx < N7) {
        int q = (int)(idx / 192), k = (int)(idx - q * 192);
        Wgb[idx] = (k < E) ? f2bf(Wih[q * E + k]) : f2bf(Whh[q * H + (k - E)]);
        return;
    }
    idx -= N7;
    if (idx < N8) { bg[idx] = bih[idx] + bhh[idx]; return; }
    idx -= N8;
    if (idx == 0) *loss = 0.0f;
}

// ---------------------------------------------------------------- fused M1+M2+LSTM+Hpart, one block per group (16 blocks)
// t>0: dh[g] = relu([h|pool][g]@Wm1^T+bm1) chunked 8x128 through LDS, chained into
//       h_prev = relu(dh@Wm2^T+bm2)  (both MFMA, B-frags from L2)
// then gates = [xe|h_prev]@Wgb^T (MFMA) -> nonlin/c -> hn; Hpart = hn@W1hb^T+biash (skip last t); rel_pos/traj/loss
__global__ __launch_bounds__(256) void lstm_step_fused(
    int t,
    const float* __restrict__ relin, const float* __restrict__ gt,
    const float* __restrict__ Wse, const float* __restrict__ bse,
    const unsigned short* __restrict__ Wgb, const float* __restrict__ bg,
    const float* __restrict__ Wpos, const float* __restrict__ bpos,
    const unsigned short* __restrict__ W1hb, const float* __restrict__ biash,
    const unsigned short* __restrict__ Wm1b, const float* __restrict__ bm1,
    const unsigned short* __restrict__ Wm2b, const float* __restrict__ bm2,
    const float* __restrict__ hh0, float* __restrict__ cbuf,
    unsigned short* __restrict__ Abf, float* __restrict__ Hpartf,
    float* __restrict__ pos, float* __restrict__ traj, float* __restrict__ loss)
{
    constexpr int LDA3 = 200;  // gates A row stride (shorts)
    constexpr int LDHB = 136;  // hn bf16 row stride
    constexpr int LDHF = 129;  // fp32 row stride
    constexpr int LDDC = 136;  // dh chunk bf16 row stride
    __shared__ __align__(16) unsigned short As3[GSZ * LDA3];  // 12800 B
    __shared__ __align__(16) unsigned short hnb[GSZ * LDHB];  //  8704 B
    __shared__ __align__(16) unsigned short dhc[GSZ * LDDC];  //  8704 B
    __shared__ float hnf[GSZ * LDHF];                         // 16512 B
    __shared__ float hpf[GSZ * LDHF];                         // 16512 B
    const int g = blockIdx.x, tid = threadIdx.x;
    const int lane = tid & 63, w = tid >> 6;
    const int quad = lane >> 4, l16 = lane & 15;

    // ---- phase 0: h_prev ----
    if (t > 0) {
        f32x4 acc2[2][2];
#pragma unroll
        for (int mt = 0; mt < 2; ++mt)
#pragma unroll
            for (int nt = 0; nt < 2; ++nt) acc2[mt][nt] = (f32x4)0.f;

        for (int nc = 0; nc < 8; ++nc) {
            // M1 chunk: dhc[32][128] = relu([h|pool][g] @ Wm1^T[nc] + bm1[nc])
            f32x4 acc1[2][2];
#pragma unroll
            for (int mt = 0; mt < 2; ++mt)
#pragma unroll
                for (int nt = 0; nt < 2; ++nt) acc1[mt][nt] = (f32x4)0.f;
#pragma unroll 6
            for (int ks = 0; ks < 36; ++ks) {
                bf16x8 af[2];
#pragma unroll
                for (int mt = 0; mt < 2; ++mt)
                    af[mt] = *(const bf16x8*)&Abf[(size_t)(g * GSZ + mt * 16 + l16) * AK + ks * 32 + quad * 8];
#pragma unroll
                for (int nt = 0; nt < 2; ++nt) {
                    int col = nc * 128 + w * 32 + nt * 16 + l16;
                    bf16x8 bf = *(const bf16x8*)&Wm1b[(size_t)col * AK + ks * 32 + quad * 8];
#pragma unroll
                    for (int mt = 0; mt < 2; ++mt)
                        acc1[mt][nt] = __builtin_amdgcn_mfma_f32_16x16x32_bf16(af[mt], bf, acc1[mt][nt], 0, 0, 0);
                }
            }
#pragma unroll
            for (int mt = 0; mt < 2; ++mt)
#pragma unroll
            for (int nt = 0; nt < 2; ++nt) {
                int col = w * 32 + nt * 16 + l16;
                float bv = bm1[nc * 128 + col];
#pragma unroll
                for (int r = 0; r < 4; ++r) {
                    int row = mt * 16 + quad * 4 + r;
                    dhc[row * LDDC + col] = f2bf(fmaxf(acc1[mt][nt][r] + bv, 0.f));
                }
            }
            __syncthreads();
            // M2 partial: acc2 += dhc @ Wm2^T[:, nc]
#pragma unroll
            for (int ks2 = 0; ks2 < 4; ++ks2) {
                bf16x8 af2[2];
#pragma unroll
                for (int mt = 0; mt < 2; ++mt)
                    af2[mt] = *(const bf16x8*)&dhc[(mt * 16 + l16) * LDDC + ks2 * 32 + quad * 8];
#pragma unroll
                for (int nt = 0; nt < 2; ++nt) {
                    int col = w * 32 + nt * 16 + l16;
                    bf16x8 bf2 = *(const bf16x8*)&Wm2b[(size_t)col * MLPD + nc * 128 + ks2 * 32 + quad * 8];
#pragma unroll
                    for (int mt = 0; mt < 2; ++mt)
                        acc2[mt][nt] = __builtin_amdgcn_mfma_f32_16x16x32_bf16(af2[mt], bf2, acc2[mt][nt], 0, 0, 0);
                }
            }
            __syncthreads();   // dhc reusable next chunk
        }
#pragma unroll
        for (int mt = 0; mt < 2; ++mt)
#pragma unroll
        for (int nt = 0; nt < 2; ++nt) {
            int col = w * 32 + nt * 16 + l16;
            float bv = bm2[col];
#pragma unroll
            for (int r = 0; r < 4; ++r) {
                int row = mt * 16 + quad * 4 + r;
                hpf[row * LDHF + col] = fmaxf(acc2[mt][nt][r] + bv, 0.f);
            }
        }
    } else {
        for (int idx = tid; idx < GSZ * H; idx += 256) {
            int row = idx >> 7, k = idx & 127;
            hpf[row * LDHF + k] = hh0[(size_t)(g * GSZ + row) * H + k];
        }
    }
    __syncthreads();

    // ---- build A = [xe | bf16(h_prev)] ----
    for (int idx = tid; idx < GSZ * 192; idx += 256) {
        int row = idx / 192, k = idx - row * 192;
        float v;
        if (k < E) {
            float rx = relin[(g * GSZ + row) * 2 + 0], ry = relin[(g * GSZ + row) * 2 + 1];
            v = bse[k] + Wse[k * 2 + 0] * rx + Wse[k * 2 + 1] * ry;
        } else {
            v = hpf[row * LDHF + (k - E)];
        }
        As3[row * LDA3 + k] = f2bf(v);
    }
    __syncthreads();

    // ---- gate GEMM ----
    f32x4 acc[2][8];
#pragma unroll
    for (int mt = 0; mt < 2; ++mt)
#pragma unroll
        for (int q = 0; q < 8; ++q) acc[mt][q] = (f32x4)0.f;
#pragma unroll
    for (int ks = 0; ks < 6; ++ks) {
        bf16x8 af[2];
#pragma unroll
        for (int mt = 0; mt < 2; ++mt)
            af[mt] = *(const bf16x8*)&As3[(mt * 16 + l16) * LDA3 + ks * 32 + quad * 8];
#pragma unroll
        for (int gate = 0; gate < 4; ++gate)
#pragma unroll
            for (int nt = 0; nt < 2; ++nt) {
                int col = gate * 128 + w * 32 + nt * 16 + l16;
                bf16x8 bf = *(const bf16x8*)&Wgb[(size_t)col * 192 + ks * 32 + quad * 8];
#pragma unroll
                for (int mt = 0; mt < 2; ++mt)
                    acc[mt][gate * 2 + nt] = __builtin_amdgcn_mfma_f32_16x16x32_bf16(af[mt], bf, acc[mt][gate * 2 + nt], 0, 0, 0);
            }
    }

    // ---- nonlinearity + c update ----
#pragma unroll
    for (int mt = 0; mt < 2; ++mt)
#pragma unroll
    for (int nt = 0; nt < 2; ++nt) {
        int u = w * 32 + nt * 16 + l16;
        float bi = bg[u], bfv = bg[128 + u], bgv = bg[256 + u], bo = bg[384 + u];
#pragma unroll
        for (int r = 0; r < 4; ++r) {
            int row = mt * 16 + quad * 4 + r;
            int b = g * GSZ + row;
            float i_ = acc[mt][0 * 2 + nt][r] + bi;
            float f_ = acc[mt][1 * 2 + nt][r] + bfv;
            float g_ = acc[mt][2 * 2 + nt][r] + bgv;
            float o_ = acc[mt][3 * 2 + nt][r] + bo;
            float ig = 1.0f / (1.0f + expf(-i_));
            float fg = 1.0f / (1.0f + expf(-f_));
            float gg = tanhf(g_);
            float og = 1.0f / (1.0f + expf(-o_));
            float c = fg * cbuf[(size_t)b * H + u] + ig * gg;
            cbuf[(size_t)b * H + u] = c;
            float h = og * tanhf(c);
            hnb[row * LDHB + u] = f2bf(h);
            hnf[row * LDHF + u] = h;
            Abf[(size_t)b * AK + u] = f2bf(h);
        }
    }
    __syncthreads();

    // ---- Hpart GEMM (dead at last step) ----
    if (t < SEQ - 1) {
        f32x4 acc2[2][8];
#pragma unroll
        for (int mt = 0; mt < 2; ++mt)
#pragma unroll
            for (int nt = 0; nt < 8; ++nt) acc2[mt][nt] = (f32x4)0.f;
#pragma unroll
        for (int ks = 0; ks < 4; ++ks) {
            bf16x8 af[2];
#pragma unroll
            for (int mt = 0; mt < 2; ++mt)
                af[mt] = *(const bf16x8*)&hnb[(mt * 16 + l16) * LDHB + ks * 32 + quad * 8];
#pragma unroll
            for (int nt = 0; nt < 8; ++nt) {
                int col = w * 128 + nt * 16 + l16;
                bf16x8 bf = *(const bf16x8*)&W1hb[(size_t)col * H + ks * 32 + quad * 8];
#pragma unroll
                for (int mt = 0; mt < 2; ++mt)
                    acc2[mt][nt] = __builtin_amdgcn_mfma_f32_16x16x32_bf16(af[mt], bf, acc2[mt][nt], 0, 0, 0);
            }
        }
#pragma unroll
        for (int mt = 0; mt < 2; ++mt)
#pragma unroll
        for (int nt = 0; nt < 8; ++nt) {
            int col = w * 128 + nt * 16 + l16;
            float bv = biash[col];
#pragma unroll
            for (int r = 0; r < 4; ++r) {
                int row = mt * 16 + quad * 4 + r;
                Hpartf[(size_t)(g * GSZ + row) * PRE + col] = acc2[mt][nt][r] + bv;
            }
        }
    }

    // ---- rel_pos / curr_pos / traj / loss ----
    if (tid < 64) {
        int row = tid >> 1, o = tid & 1;
        float acc3 = bpos[o];
        const float* wr = Wpos + o * H;
        for (int k = 0; k < H; ++k) acc3 += wr[k] * hnf[row * LDHF + k];
        int b = g * GSZ + row;
        float lp = pos[b * 2 + o];
        pos[b * 2 + o] = acc3 + lp;
        traj[b * 2 + o] = acc3;
        float d = acc3 - gt[b * 2 + o];
        atomicAdd(loss, d * d * (1.0f / 1024.0f));
    }
}

// ---------------------------------------------------------------- pool GEMM2 (R10-proven, verbatim: BN=128, grid 1024)
__global__ __launch_bounds__(256) void pool_gemm(
    const float* __restrict__ Hpartf, const float* __restrict__ pos,
    const float* __restrict__ Wcx, const float* __restrict__ Wcy,
    const unsigned short* __restrict__ W2b,
    const float* __restrict__ b2, unsigned short* __restrict__ Abf)
{
    constexpr int BM = 128, BN = 128, MT = 4, NT = 4;
    constexpr int LDA = 72;
    __shared__ __align__(16) unsigned short As[BM * LDA];
    __shared__ __align__(16) unsigned short Bs[BN * 64];
    __shared__ float red[4 * 128];
    __shared__ float px[GSZ], py[GSZ];
    int tid = threadIdx.x;
    int lane = tid & 63, w = tid >> 6, wm = w >> 1, wn = w & 1;
    int quad = lane >> 4, l16 = lane & 15;
    int bid = blockIdx.x;
    int m_tile = ((bid & 7) << 4) | (bid >> 6);
    int n_tile = (bid >> 3) & 7;
    int g = m_tile >> 3, iq = m_tile & 7;
    int n0 = n_tile * BN;

    if (tid < GSZ) { px[tid] = pos[(g * GSZ + tid) * 2]; py[tid] = pos[(g * GSZ + tid) * 2 + 1]; }

    f32x4 acc[MT][NT];
#pragma unroll
    for (int mt = 0; mt < MT; ++mt)
#pragma unroll
        for (int nt = 0; nt < NT; ++nt) acc[mt][nt] = (f32x4)0.f;

    int jA = tid >> 3, k8 = (tid & 7) * 8;
    __syncthreads();
    float pjx = px[jA], pjy = py[jA];

    for (int k0 = 0; k0 < PRE; k0 += 64) {
#pragma unroll
        for (int it = 0; it < 4; ++it) {
            int c = it * 256 + tid;
            __builtin_amdgcn_global_load_lds(
                GLB(W2b + (size_t)(n0 + (c >> 3)) * PRE + k0 + (c & 7) * 8),
                LDS(&Bs[c * 8]), 16, 0, 0);
        }
        {
            const float4* hp4 = (const float4*)&Hpartf[(size_t)(g * GSZ + jA) * PRE + k0 + k8];
            float4 ha = hp4[0], hb = hp4[1];
            float4 wxa = *(const float4*)&Wcx[k0 + k8], wxb = *(const float4*)&Wcx[k0 + k8 + 4];
            float4 wya = *(const float4*)&Wcy[k0 + k8], wyb = *(const float4*)&Wcy[k0 + k8 + 4];
#pragma unroll
            for (int u = 0; u < 4; ++u) {
                int i = iq * 4 + u;
                float rx = pjx - px[i], ry = pjy - py[i];
                union { ushort s[8]; uint4 v; } o;
                o.s[0] = f2bf(fmaxf(ha.x + rx * wxa.x + ry * wya.x, 0.f));
                o.s[1] = f2bf(fmaxf(ha.y + rx * wxa.y + ry * wya.y, 0.f));
                o.s[2] = f2bf(fmaxf(ha.z + rx * wxa.z + ry * wya.z, 0.f));
                o.s[3] = f2bf(fmaxf(ha.w + rx * wxa.w + ry * wya.w, 0.f));
                o.s[4] = f2bf(fmaxf(hb.x + rx * wxb.x + ry * wyb.x, 0.f));
                o.s[5] = f2bf(fmaxf(hb.y + rx * wxb.y + ry * wyb.y, 0.f));
                o.s[6] = f2bf(fmaxf(hb.z + rx * wxb.z + ry * wyb.z, 0.f));
                o.s[7] = f2bf(fmaxf(hb.w + rx * wxb.w + ry * wyb.w, 0.f));
                *(uint4*)&As[(u * GSZ + jA) * LDA + k8] = o.v;
            }
        }
        __syncthreads();
#pragma unroll
        for (int ks = 0; ks < 2; ++ks) {
            bf16x8 af[MT], bfr[NT];
#pragma unroll
            for (int mt = 0; mt < MT; ++mt)
                af[mt] = *(const bf16x8*)&As[(wm * 64 + mt * 16 + l16) * LDA + ks * 32 + quad * 8];
#pragma unroll
            for (int nt = 0; nt < NT; ++nt)
                bfr[nt] = *(const bf16x8*)&Bs[(wn * 64 + nt * 16 + l16) * 64 + ks * 32 + quad * 8];
#pragma unroll
            for (int mt = 0; mt < MT; ++mt)
#pragma unroll
                for (int nt = 0; nt < NT; ++nt)
                    acc[mt][nt] = __builtin_amdgcn_mfma_f32_16x16x32_bf16(af[mt], bfr[nt], acc[mt][nt], 0, 0, 0);
        }
        __syncthreads();
    }

#pragma unroll
    for (int nt = 0; nt < NT; ++nt) {
        float u0 = -1e30f, u1 = -1e30f;
#pragma unroll
        for (int r = 0; r < 4; ++r) {
            u0 = fmaxf(u0, fmaxf(acc[0][nt][r], acc[1][nt][r]));
            u1 = fmaxf(u1, fmaxf(acc[2][nt][r], acc[3][nt][r]));
        }
        u0 = fmaxf(u0, __shfl_xor(u0, 16)); u0 = fmaxf(u0, __shfl_xor(u0, 32));
        u1 = fmaxf(u1, __shfl_xor(u1, 16)); u1 = fmaxf(u1, __shfl_xor(u1, 32));
        if (lane < 16) {
            red[(wm * 2 + 0) * 128 + wn * 64 + nt * 16 + lane] = u0;
            red[(wm * 2 + 1) * 128 + wn * 64 + nt * 16 + lane] = u1;
        }
    }
    __syncthreads();
    for (int e = tid; e < 512; e += 256) {
        int u = e >> 7, cc = e & 127;
        int gu = m_tile * 4 + u;
        float v = fmaxf(red[e] + b2[n0 + cc], 0.f);
        Abf[(size_t)gu * AK + H + n0 + cc] = f2bf(v);
    }
}

// ---------------------------------------------------------------- launch
extern "C" void kernel_launch(void* const* d_in, const int* in_sizes, int n_in,
                              void* d_out, int out_size, void* d_ws, size_t ws_size,
                              hipStream_t stream)
{
    const float* last_pos     = (const float*)d_in[0];
    const float* last_pos_rel = (const float*)d_in[1];
    const float* hh           = (const float*)d_in[2];
    const float* ch           = (const float*)d_in[3];
    const float* ptr_rel      = (const float*)d_in[4];
    const float* Wih  = (const float*)d_in[6];
    const float* Whh  = (const float*)d_in[7];
    const float* bih  = (const float*)d_in[8];
    const float* bhh  = (const float*)d_in[9];
    const float* Wse  = (const float*)d_in[10];
    const float* bse  = (const float*)d_in[11];
    const float* Wpos = (const float*)d_in[12];
    const float* bpos = (const float*)d_in[13];
    const float* Wp   = (const float*)d_in[14];
    const float* bp   = (const float*)d_in[15];
    const float* W1   = (const float*)d_in[16];
    const float* b1   = (const float*)d_in[17];
    const float* W2   = (const float*)d_in[18];
    const float* b2   = (const float*)d_in[19];
    const float* Wm1  = (const float*)d_in[20];
    const float* bm1  = (const float*)d_in[21];
    const float* Wm2  = (const float*)d_in[22];
    const float* bm2  = (const float*)d_in[23];

    float* ws     = (float*)d_ws;
    float* cbuf   = ws;                       // 65536
    float* pos    = cbuf + BATCH * H;         // 1024 (padded)
    float* Hpartf = pos + 1024;               // 262144
    float* Wcx    = Hpartf + BATCH * PRE;     // 512
    float* Wcy    = Wcx + PRE;                // 512
    float* biash  = Wcy + PRE;                // 512
    float* bg     = biash + PRE;              // 512
    unsigned short* ub    = (unsigned short*)(bg + 512);
    unsigned short* Abf   = ub;                         // 512*1152
    unsigned short* W2b   = Abf + (size_t)BATCH * AK;
    unsigned short* Wm1b  = W2b + (size_t)BOT * PRE;
    unsigned short* Wm2b  = Wm1b + (size_t)MLPD * AK;
    unsigned short* W1hb  = Wm2b + (size_t)H * MLPD;    // 512*128
    unsigned short* Wgb   = W1hb + (size_t)PRE * H;     // 512*192

    float* out  = (float*)d_out;
    float* loss = out + SEQ * BATCH * 2;

    prep_kernel<<<(PREP_TOT + 255) / 256, 256, 0, stream>>>(
        W2, Wm1, Wm2, W1, Wp, bp, b1, ch, last_pos, Wih, Whh, bih, bhh,
        W2b, Wm1b, Wm2b, W1hb, Wcx, Wcy, biash, cbuf, pos, Wgb, bg, loss);

    for (int t = 0; t < SEQ; t++) {
        const float* relin = (t == 0) ? last_pos_rel : (ptr_rel + (t - 1) * BATCH * 2);
        const float* gt = ptr_rel + t * BATCH * 2;
        // fused M1+M2 (prev step's [h|pool] -> h_prev) + LSTM gates + Hpart + rel_pos/loss
        lstm_step_fused<<<NG, 256, 0, stream>>>(t, relin, gt, Wse, bse, Wgb, bg, Wpos, bpos,
                                                W1hb, biash, Wm1b, bm1, Wm2b, bm2, hh,
                                                cbuf, Abf, Hpartf, pos,
                                                out + t * BATCH * 2, loss);
        if (t == SEQ - 1) break;   // pool/MLP after last step are dead
        // pool: fused x1-build + X2 GEMM + max_j -> Abf[:,128:]
        pool_gemm<<<1024, 256, 0, stream>>>(Hpartf, pos, Wcx, Wcy, W2b, b2, Abf);
    }
}

// Round 13
// 1097.538 us; speedup vs baseline: 2.4572x; 2.4572x over previous
//
#include <hip/hip_runtime.h>
#include <math.h>

#define BATCH 512
#define NG 16
#define GSZ 32
#define H 128
#define E 64
#define PRE 512
#define BOT 1024
#define MLPD 1024
#define SEQ 12
#define AK 1152   // Abf row length = H + BOT

typedef __attribute__((ext_vector_type(8))) short bf16x8;
typedef __attribute__((ext_vector_type(4))) float f32x4;

__device__ __forceinline__ unsigned short f2bf(float f) {
    unsigned u = __float_as_uint(f);
    u += 0x7FFF + ((u >> 16) & 1);   // round-to-nearest-even
    return (unsigned short)(u >> 16);
}
__device__ __forceinline__ float bf2f(unsigned short s) {
    return __uint_as_float(((unsigned)s) << 16);
}

#define GLB(p) ((const __attribute__((address_space(1))) unsigned int*)(p))
#define LDS(p) ((__attribute__((address_space(3))) unsigned int*)(p))

// ---------------------------------------------------------------- one-shot prep
#define N0 (BOT * PRE)        /* W2b   */
#define N1 (MLPD * AK)        /* Wm1b  */
#define N2 (H * MLPD)         /* Wm2b  */
#define N3 (PRE * H)          /* W1hb  */
#define N4 (PRE)              /* wc    */
#define N5 (BATCH * H)        /* c     */
#define N6 (BATCH * 2)        /* pos   */
#define N7 (512 * 192)        /* Wgb = [Wih|Whh] bf16 */
#define N8 (512)              /* bg = bih+bhh */
#define PREP_TOT (N0 + N1 + N2 + N3 + N4 + N5 + N6 + N7 + N8 + 1)

__global__ void prep_kernel(
    const float* __restrict__ W2, const float* __restrict__ Wm1,
    const float* __restrict__ Wm2, const float* __restrict__ W1,
    const float* __restrict__ Wp, const float* __restrict__ bp, const float* __restrict__ b1,
    const float* __restrict__ ch, const float* __restrict__ last_pos,
    const float* __restrict__ Wih, const float* __restrict__ Whh,
    const float* __restrict__ bih, const float* __restrict__ bhh,
    unsigned short* __restrict__ W2b, unsigned short* __restrict__ Wm1b,
    unsigned short* __restrict__ Wm2b, unsigned short* __restrict__ W1hb,
    float* __restrict__ Wcx, float* __restrict__ Wcy, float* __restrict__ biash,
    float* __restrict__ cbuf, float* __restrict__ pos,
    unsigned short* __restrict__ Wgb, float* __restrict__ bg,
    float* __restrict__ loss)
{
    long idx = (long)blockIdx.x * 256 + threadIdx.x;
    if (idx < N0) { W2b[idx] = f2bf(W2[idx]); return; }
    idx -= N0;
    if (idx < N1) { Wm1b[idx] = f2bf(Wm1[idx]); return; }
    idx -= N1;
    if (idx < N2) { Wm2b[idx] = f2bf(Wm2[idx]); return; }
    idx -= N2;
    if (idx < N3) { int r = (int)(idx >> 7), c = (int)(idx & 127);
                    W1hb[idx] = f2bf(W1[r * 192 + E + c]); return; }
    idx -= N3;
    if (idx < N4) {
        int p = (int)idx;
        float sx = 0.f, sy = 0.f, sb = 0.f;
#pragma unroll 8
        for (int e = 0; e < E; ++e) {
            float w = W1[p * 192 + e];
            sx += w * Wp[e * 2 + 0];
            sy += w * Wp[e * 2 + 1];
            sb += w * bp[e];
        }
        Wcx[p] = sx; Wcy[p] = sy; biash[p] = b1[p] + sb;
        return;
    }
    idx -= N4;
    if (idx < N5) { cbuf[idx] = ch[idx]; return; }
    idx -= N5;
    if (idx < N6) { pos[idx] = last_pos[idx]; return; }
    idx -= N6;
    if (idx < N7) {
        int q = (int)(idx / 192), k = (int)(idx - q * 192);
        Wgb[idx] = (k < E) ? f2bf(Wih[q * E + k]) : f2bf(Whh[q * H + (k - E)]);
        return;
    }
    idx -= N7;
    if (idx < N8) { bg[idx] = bih[idx] + bhh[idx]; return; }
    idx -= N8;
    if (idx == 0) *loss = 0.0f;
}

// ---------------------------------------------------------------- fused LSTM + Hpart, one block per group (R10-proven)
__global__ __launch_bounds__(256) void lstm_hpart(
    int t,
    const float* __restrict__ relin, const float* __restrict__ gt,
    const float* __restrict__ Wse, const float* __restrict__ bse,
    const unsigned short* __restrict__ Wgb, const float* __restrict__ bg,
    const float* __restrict__ Wpos, const float* __restrict__ bpos,
    const unsigned short* __restrict__ W1hb, const float* __restrict__ biash,
    const float* __restrict__ hbuf, float* __restrict__ cbuf,
    unsigned short* __restrict__ Abf, float* __restrict__ Hpartf,
    float* __restrict__ pos, float* __restrict__ traj, float* __restrict__ loss)
{
    constexpr int LDA3 = 200;
    constexpr int LDHB = 136;
    constexpr int LDHF = 129;
    __shared__ __align__(16) unsigned short As[GSZ * LDA3];
    __shared__ __align__(16) unsigned short hnb[GSZ * LDHB];
    __shared__ float hnf[GSZ * LDHF];
    const int g = blockIdx.x, tid = threadIdx.x;
    const int lane = tid & 63, w = tid >> 6;
    const int quad = lane >> 4, l16 = lane & 15;

    // ---- build A = [xe | bf16(h_in)] ----
    for (int idx = tid; idx < GSZ * 192; idx += 256) {
        int row = idx / 192, k = idx - row * 192;
        float v;
        if (k < E) {
            float rx = relin[(g * GSZ + row) * 2 + 0], ry = relin[(g * GSZ + row) * 2 + 1];
            v = bse[k] + Wse[k * 2 + 0] * rx + Wse[k * 2 + 1] * ry;
        } else {
            v = hbuf[(size_t)(g * GSZ + row) * H + (k - E)];
        }
        As[row * LDA3 + k] = f2bf(v);
    }
    __syncthreads();

    // ---- gate GEMM ----
    f32x4 acc[2][8];
#pragma unroll
    for (int mt = 0; mt < 2; ++mt)
#pragma unroll
        for (int q = 0; q < 8; ++q) acc[mt][q] = (f32x4)0.f;
#pragma unroll
    for (int ks = 0; ks < 6; ++ks) {
        bf16x8 af[2];
#pragma unroll
        for (int mt = 0; mt < 2; ++mt)
            af[mt] = *(const bf16x8*)&As[(mt * 16 + l16) * LDA3 + ks * 32 + quad * 8];
#pragma unroll
        for (int gate = 0; gate < 4; ++gate)
#pragma unroll
            for (int nt = 0; nt < 2; ++nt) {
                int col = gate * 128 + w * 32 + nt * 16 + l16;
                bf16x8 bf = *(const bf16x8*)&Wgb[(size_t)col * 192 + ks * 32 + quad * 8];
#pragma unroll
                for (int mt = 0; mt < 2; ++mt)
                    acc[mt][gate * 2 + nt] = __builtin_amdgcn_mfma_f32_16x16x32_bf16(af[mt], bf, acc[mt][gate * 2 + nt], 0, 0, 0);
            }
    }

    // ---- nonlinearity + c update ----
#pragma unroll
    for (int mt = 0; mt < 2; ++mt)
#pragma unroll
    for (int nt = 0; nt < 2; ++nt) {
        int u = w * 32 + nt * 16 + l16;
        float bi = bg[u], bfv = bg[128 + u], bgv = bg[256 + u], bo = bg[384 + u];
#pragma unroll
        for (int r = 0; r < 4; ++r) {
            int row = mt * 16 + quad * 4 + r;
            int b = g * GSZ + row;
            float i_ = acc[mt][0 * 2 + nt][r] + bi;
            float f_ = acc[mt][1 * 2 + nt][r] + bfv;
            float g_ = acc[mt][2 * 2 + nt][r] + bgv;
            float o_ = acc[mt][3 * 2 + nt][r] + bo;
            float ig = 1.0f / (1.0f + expf(-i_));
            float fg = 1.0f / (1.0f + expf(-f_));
            float gg = tanhf(g_);
            float og = 1.0f / (1.0f + expf(-o_));
            float c = fg * cbuf[(size_t)b * H + u] + ig * gg;
            cbuf[(size_t)b * H + u] = c;
            float h = og * tanhf(c);
            hnb[row * LDHB + u] = f2bf(h);
            hnf[row * LDHF + u] = h;
            Abf[(size_t)b * AK + u] = f2bf(h);
        }
    }
    __syncthreads();

    // ---- Hpart GEMM (dead at last step) ----
    if (t < SEQ - 1) {
        f32x4 acc2[2][8];
#pragma unroll
        for (int mt = 0; mt < 2; ++mt)
#pragma unroll
            for (int nt = 0; nt < 8; ++nt) acc2[mt][nt] = (f32x4)0.f;
#pragma unroll
        for (int ks = 0; ks < 4; ++ks) {
            bf16x8 af[2];
#pragma unroll
            for (int mt = 0; mt < 2; ++mt)
                af[mt] = *(const bf16x8*)&hnb[(mt * 16 + l16) * LDHB + ks * 32 + quad * 8];
#pragma unroll
            for (int nt = 0; nt < 8; ++nt) {
                int col = w * 128 + nt * 16 + l16;
                bf16x8 bf = *(const bf16x8*)&W1hb[(size_t)col * H + ks * 32 + quad * 8];
#pragma unroll
                for (int mt = 0; mt < 2; ++mt)
                    acc2[mt][nt] = __builtin_amdgcn_mfma_f32_16x16x32_bf16(af[mt], bf, acc2[mt][nt], 0, 0, 0);
            }
        }
#pragma unroll
        for (int mt = 0; mt < 2; ++mt)
#pragma unroll
        for (int nt = 0; nt < 8; ++nt) {
            int col = w * 128 + nt * 16 + l16;
            float bv = biash[col];
#pragma unroll
            for (int r = 0; r < 4; ++r) {
                int row = mt * 16 + quad * 4 + r;
                Hpartf[(size_t)(g * GSZ + row) * PRE + col] = acc2[mt][nt][r] + bv;
            }
        }
    }

    // ---- rel_pos / curr_pos / traj / loss ----
    if (tid < 64) {
        int row = tid >> 1, o = tid & 1;
        float acc3 = bpos[o];
        const float* wr = Wpos + o * H;
        for (int k = 0; k < H; ++k) acc3 += wr[k] * hnf[row * LDHF + k];
        int b = g * GSZ + row;
        float lp = pos[b * 2 + o];
        pos[b * 2 + o] = acc3 + lp;
        traj[b * 2 + o] = acc3;
        float d = acc3 - gt[b * 2 + o];
        atomicAdd(loss, d * d * (1.0f / 1024.0f));
    }
}

// ---------------------------------------------------------------- generic bf16 MFMA GEMM  C = A(MxK) @ B(NxK)^T
// MODE 1: Cb = bf16(relu(acc+bias)) | MODE 2: Cf = relu(acc+bias)  (R5/R10-proven)
template <int BM, int BN, int MODE>
__global__ __launch_bounds__(256) void gemm_mfma(
    const unsigned short* __restrict__ A, int lda,
    const unsigned short* __restrict__ B, int ldb, int K,
    const float* __restrict__ bias,
    float* __restrict__ Cf, unsigned short* __restrict__ Cb, int ldc)
{
    constexpr int MT = BM / 32, NT = BN / 32;
    __shared__ __align__(16) unsigned short As[BM * 64];
    __shared__ __align__(16) unsigned short Bs[BN * 64];
    int tid = threadIdx.x;
    int lane = tid & 63, w = tid >> 6, wm = w >> 1, wn = w & 1;
    int quad = lane >> 4, l16 = lane & 15;
    int m0 = blockIdx.y * BM, n0 = blockIdx.x * BN;

    f32x4 acc[MT][NT];
#pragma unroll
    for (int mt = 0; mt < MT; ++mt)
#pragma unroll
        for (int nt = 0; nt < NT; ++nt) acc[mt][nt] = (f32x4)0.f;

    for (int k0 = 0; k0 < K; k0 += 64) {
#pragma unroll
        for (int it = 0; it < BM / 32; ++it) {
            int c = it * 256 + tid;
            __builtin_amdgcn_global_load_lds(
                GLB(A + (size_t)(m0 + (c >> 3)) * lda + k0 + (c & 7) * 8),
                LDS(&As[c * 8]), 16, 0, 0);
        }
#pragma unroll
        for (int it = 0; it < BN / 32; ++it) {
            int c = it * 256 + tid;
            __builtin_amdgcn_global_load_lds(
                GLB(B + (size_t)(n0 + (c >> 3)) * ldb + k0 + (c & 7) * 8),
                LDS(&Bs[c * 8]), 16, 0, 0);
        }
        __syncthreads();
#pragma unroll
        for (int ks = 0; ks < 2; ++ks) {
            bf16x8 af[MT], bfr[NT];
#pragma unroll
            for (int mt = 0; mt < MT; ++mt)
                af[mt] = *(const bf16x8*)&As[(wm * (BM / 2) + mt * 16 + l16) * 64 + ks * 32 + quad * 8];
#pragma unroll
            for (int nt = 0; nt < NT; ++nt)
                bfr[nt] = *(const bf16x8*)&Bs[(wn * (BN / 2) + nt * 16 + l16) * 64 + ks * 32 + quad * 8];
#pragma unroll
            for (int mt = 0; mt < MT; ++mt)
#pragma unroll
                for (int nt = 0; nt < NT; ++nt)
                    acc[mt][nt] = __builtin_amdgcn_mfma_f32_16x16x32_bf16(af[mt], bfr[nt], acc[mt][nt], 0, 0, 0);
        }
        __syncthreads();
    }

#pragma unroll
    for (int mt = 0; mt < MT; ++mt) {
        int rbase = m0 + wm * (BM / 2) + mt * 16 + quad * 4;
#pragma unroll
        for (int nt = 0; nt < NT; ++nt) {
            int col = n0 + wn * (BN / 2) + nt * 16 + l16;
            float bv = bias[col];
#pragma unroll
            for (int r = 0; r < 4; ++r) {
                float v = acc[mt][nt][r] + bv;
                v = fmaxf(v, 0.f);
                if (MODE == 1) Cb[(size_t)(rbase + r) * ldc + col] = f2bf(v);
                else           Cf[(size_t)(rbase + r) * ldc + col] = v;
            }
        }
    }
}

// ---------------------------------------------------------------- pool GEMM2 (R10-proven, verbatim)
__global__ __launch_bounds__(256) void pool_gemm(
    const float* __restrict__ Hpartf, const float* __restrict__ pos,
    const float* __restrict__ Wcx, const float* __restrict__ Wcy,
    const unsigned short* __restrict__ W2b,
    const float* __restrict__ b2, unsigned short* __restrict__ Abf)
{
    constexpr int BM = 128, BN = 128, MT = 4, NT = 4;
    constexpr int LDA = 72;
    __shared__ __align__(16) unsigned short As[BM * LDA];
    __shared__ __align__(16) unsigned short Bs[BN * 64];
    __shared__ float red[4 * 128];
    __shared__ float px[GSZ], py[GSZ];
    int tid = threadIdx.x;
    int lane = tid & 63, w = tid >> 6, wm = w >> 1, wn = w & 1;
    int quad = lane >> 4, l16 = lane & 15;
    int bid = blockIdx.x;
    int m_tile = ((bid & 7) << 4) | (bid >> 6);
    int n_tile = (bid >> 3) & 7;
    int g = m_tile >> 3, iq = m_tile & 7;
    int n0 = n_tile * BN;

    if (tid < GSZ) { px[tid] = pos[(g * GSZ + tid) * 2]; py[tid] = pos[(g * GSZ + tid) * 2 + 1]; }

    f32x4 acc[MT][NT];
#pragma unroll
    for (int mt = 0; mt < MT; ++mt)
#pragma unroll
        for (int nt = 0; nt < NT; ++nt) acc[mt][nt] = (f32x4)0.f;

    int jA = tid >> 3, k8 = (tid & 7) * 8;
    __syncthreads();
    float pjx = px[jA], pjy = py[jA];

    for (int k0 = 0; k0 < PRE; k0 += 64) {
#pragma unroll
        for (int it = 0; it < 4; ++it) {
            int c = it * 256 + tid;
            __builtin_amdgcn_global_load_lds(
                GLB(W2b + (size_t)(n0 + (c >> 3)) * PRE + k0 + (c & 7) * 8),
                LDS(&Bs[c * 8]), 16, 0, 0);
        }
        {
            const float4* hp4 = (const float4*)&Hpartf[(size_t)(g * GSZ + jA) * PRE + k0 + k8];
            float4 ha = hp4[0], hb = hp4[1];
            float4 wxa = *(const float4*)&Wcx[k0 + k8], wxb = *(const float4*)&Wcx[k0 + k8 + 4];
            float4 wya = *(const float4*)&Wcy[k0 + k8], wyb = *(const float4*)&Wcy[k0 + k8 + 4];
#pragma unroll
            for (int u = 0; u < 4; ++u) {
                int i = iq * 4 + u;
                float rx = pjx - px[i], ry = pjy - py[i];
                union { ushort s[8]; uint4 v; } o;
                o.s[0] = f2bf(fmaxf(ha.x + rx * wxa.x + ry * wya.x, 0.f));
                o.s[1] = f2bf(fmaxf(ha.y + rx * wxa.y + ry * wya.y, 0.f));
                o.s[2] = f2bf(fmaxf(ha.z + rx * wxa.z + ry * wya.z, 0.f));
                o.s[3] = f2bf(fmaxf(ha.w + rx * wxa.w + ry * wya.w, 0.f));
                o.s[4] = f2bf(fmaxf(hb.x + rx * wxb.x + ry * wyb.x, 0.f));
                o.s[5] = f2bf(fmaxf(hb.y + rx * wxb.y + ry * wyb.y, 0.f));
                o.s[6] = f2bf(fmaxf(hb.z + rx * wxb.z + ry * wyb.z, 0.f));
                o.s[7] = f2bf(fmaxf(hb.w + rx * wxb.w + ry * wyb.w, 0.f));
                *(uint4*)&As[(u * GSZ + jA) * LDA + k8] = o.v;
            }
        }
        __syncthreads();
#pragma unroll
        for (int ks = 0; ks < 2; ++ks) {
            bf16x8 af[MT], bfr[NT];
#pragma unroll
            for (int mt = 0; mt < MT; ++mt)
                af[mt] = *(const bf16x8*)&As[(wm * 64 + mt * 16 + l16) * LDA + ks * 32 + quad * 8];
#pragma unroll
            for (int nt = 0; nt < NT; ++nt)
                bfr[nt] = *(const bf16x8*)&Bs[(wn * 64 + nt * 16 + l16) * 64 + ks * 32 + quad * 8];
#pragma unroll
            for (int mt = 0; mt < MT; ++mt)
#pragma unroll
                for (int nt = 0; nt < NT; ++nt)
                    acc[mt][nt] = __builtin_amdgcn_mfma_f32_16x16x32_bf16(af[mt], bfr[nt], acc[mt][nt], 0, 0, 0);
        }
        __syncthreads();
    }

#pragma unroll
    for (int nt = 0; nt < NT; ++nt) {
        float u0 = -1e30f, u1 = -1e30f;
#pragma unroll
        for (int r = 0; r < 4; ++r) {
            u0 = fmaxf(u0, fmaxf(acc[0][nt][r], acc[1][nt][r]));
            u1 = fmaxf(u1, fmaxf(acc[2][nt][r], acc[3][nt][r]));
        }
        u0 = fmaxf(u0, __shfl_xor(u0, 16)); u0 = fmaxf(u0, __shfl_xor(u0, 32));
        u1 = fmaxf(u1, __shfl_xor(u1, 16)); u1 = fmaxf(u1, __shfl_xor(u1, 32));
        if (lane < 16) {
            red[(wm * 2 + 0) * 128 + wn * 64 + nt * 16 + lane] = u0;
            red[(wm * 2 + 1) * 128 + wn * 64 + nt * 16 + lane] = u1;
        }
    }
    __syncthreads();
    for (int e = tid; e < 512; e += 256) {
        int u = e >> 7, cc = e & 127;
        int gu = m_tile * 4 + u;
        float v = fmaxf(red[e] + b2[n0 + cc], 0.f);
        Abf[(size_t)gu * AK + H + n0 + cc] = f2bf(v);
    }
}

// ---------------------------------------------------------------- launch
extern "C" void kernel_launch(void* const* d_in, const int* in_sizes, int n_in,
                              void* d_out, int out_size, void* d_ws, size_t ws_size,
                              hipStream_t stream)
{
    const float* last_pos     = (const float*)d_in[0];
    const float* last_pos_rel = (const float*)d_in[1];
    const float* hh           = (const float*)d_in[2];
    const float* ch           = (const float*)d_in[3];
    const float* ptr_rel      = (const float*)d_in[4];
    const float* Wih  = (const float*)d_in[6];
    const float* Whh  = (const float*)d_in[7];
    const float* bih  = (const float*)d_in[8];
    const float* bhh  = (const float*)d_in[9];
    const float* Wse  = (const float*)d_in[10];
    const float* bse  = (const float*)d_in[11];
    const float* Wpos = (const float*)d_in[12];
    const float* bpos = (const float*)d_in[13];
    const float* Wp   = (const float*)d_in[14];
    const float* bp   = (const float*)d_in[15];
    const float* W1   = (const float*)d_in[16];
    const float* b1   = (const float*)d_in[17];
    const float* W2   = (const float*)d_in[18];
    const float* b2   = (const float*)d_in[19];
    const float* Wm1  = (const float*)d_in[20];
    const float* bm1  = (const float*)d_in[21];
    const float* Wm2  = (const float*)d_in[22];
    const float* bm2  = (const float*)d_in[23];

    float* ws     = (float*)d_ws;
    float* hbuf   = ws;                       // 65536
    float* cbuf   = hbuf + BATCH * H;         // 65536
    float* pos    = cbuf + BATCH * H;         // 1024 (padded)
    float* Hpartf = pos + 1024;               // 262144
    float* Wcx    = Hpartf + BATCH * PRE;     // 512
    float* Wcy    = Wcx + PRE;                // 512
    float* biash  = Wcy + PRE;                // 512
    float* bg     = biash + PRE;              // 512
    unsigned short* ub    = (unsigned short*)(bg + 512);
    unsigned short* Abf   = ub;                         // 512*1152
    unsigned short* dhbf  = Abf + (size_t)BATCH * AK;   // 512*1024
    unsigned short* W2b   = dhbf + (size_t)BATCH * MLPD;
    unsigned short* Wm1b  = W2b + (size_t)BOT * PRE;
    unsigned short* Wm2b  = Wm1b + (size_t)MLPD * AK;
    unsigned short* W1hb  = Wm2b + (size_t)H * MLPD;    // 512*128
    unsigned short* Wgb   = W1hb + (size_t)PRE * H;     // 512*192

    float* out  = (float*)d_out;
    float* loss = out + SEQ * BATCH * 2;

    prep_kernel<<<(PREP_TOT + 255) / 256, 256, 0, stream>>>(
        W2, Wm1, Wm2, W1, Wp, bp, b1, ch, last_pos, Wih, Whh, bih, bhh,
        W2b, Wm1b, Wm2b, W1hb, Wcx, Wcy, biash, cbuf, pos, Wgb, bg, loss);

    for (int t = 0; t < SEQ; t++) {
        const float* relin = (t == 0) ? last_pos_rel : (ptr_rel + (t - 1) * BATCH * 2);
        const float* gt = ptr_rel + t * BATCH * 2;
        // fused LSTM gates (MFMA) + Hpart (MFMA) + rel_pos/loss   [R10-proven]
        lstm_hpart<<<NG, 256, 0, stream>>>(t, relin, gt, Wse, bse, Wgb, bg, Wpos, bpos,
                                           W1hb, biash, hbuf, cbuf, Abf, Hpartf, pos,
                                           out + t * BATCH * 2, loss);
        if (t == SEQ - 1) break;   // h after last step is dead
        // pool: fused x1-build + X2 GEMM + max_j -> Abf[:,128:]   [R10-proven]
        pool_gemm<<<1024, 256, 0, stream>>>(Hpartf, pos, Wcx, Wcy, W2b, b2, Abf);
        // dh = bf16(relu([h|pool] @ Wm1^T + bm1))  — 64x32 tiles, 256 blocks (R12 delta: better CU coverage)
        gemm_mfma<64, 32, 1><<<dim3(MLPD / 32, BATCH / 64), 256, 0, stream>>>(
            Abf, AK, Wm1b, AK, AK, bm1, nullptr, dhbf, MLPD);
        // h = relu(dh @ Wm2^T + bm2) -> fp32 hbuf   [R10-proven]
        gemm_mfma<64, 32, 2><<<dim3(H / 32, BATCH / 64), 256, 0, stream>>>(
            dhbf, MLPD, Wm2b, MLPD, MLPD, bm2, hbuf, nullptr, H);
    }
}